// Round 1
// baseline (783.056 us; speedup 1.0000x reference)
//
#include <hip/hip_runtime.h>
#include <cstdint>

// Problem constants
#define BATCH 8
#define HGT 128
#define WID 128
#define CHN 256
#define HWID 65   // half-spectrum width (W/2+1)

typedef __attribute__((ext_vector_type(4))) float f32x4;
typedef __attribute__((ext_vector_type(8))) _Float16 f16x8;
typedef __attribute__((ext_vector_type(4))) _Float16 f16x4;

__device__ __forceinline__ float2 cmulf(float2 a, float2 b) {
  return make_float2(fmaf(a.x, b.x, -a.y * b.y), fmaf(a.x, b.y, a.y * b.x));
}

__device__ __forceinline__ void gload_lds16(const _Float16* g, _Float16* l) {
  __builtin_amdgcn_global_load_lds((const __attribute__((address_space(1))) unsigned int*)g,
                                   (__attribute__((address_space(3))) unsigned int*)l, 16, 0, 0);
}

// ---------------- weight packing: Wt[p=d*4+proj][k] fp16 ----------------
__global__ __launch_bounds__(256) void prep_w(const float* __restrict__ Wma, const float* __restrict__ Wpa,
                                              const float* __restrict__ Wmb, const float* __restrict__ Wpb,
                                              _Float16* __restrict__ Wt) {
  int k = blockIdx.x, d = threadIdx.x;
  Wt[(d * 4 + 0) * 256 + k] = (_Float16)Wma[k * 256 + d];
  Wt[(d * 4 + 1) * 256 + k] = (_Float16)Wpa[k * 256 + d];
  Wt[(d * 4 + 2) * 256 + k] = (_Float16)Wmb[k * 256 + d];
  Wt[(d * 4 + 3) * 256 + k] = (_Float16)Wpb[k * 256 + d];
}

// ---------------- kernel->freq, stage 1: DFT over j (7 taps) ----------------
// tA[i][v][c] = sum_j K[c,i,j] * e^{-2pi i v(j-3)/128}, v in [0,65)
__global__ __launch_bounds__(256) void kfreq1(const float* __restrict__ KA, const float* __restrict__ KB,
                                              float2* __restrict__ tA, float2* __restrict__ tB) {
  int i = blockIdx.x / HWID, v = blockIdx.x % HWID, c = threadIdx.x;
  const float w0 = -6.2831853071795864769f / 128.0f;
  float2 sa = make_float2(0.f, 0.f), sb = make_float2(0.f, 0.f);
#pragma unroll
  for (int j = 0; j < 7; ++j) {
    float ang = w0 * (float)(v * (j - 3));
    float sn, cs;
    sincosf(ang, &sn, &cs);
    float ka = KA[c * 49 + i * 7 + j];
    float kb = KB[c * 49 + i * 7 + j];
    sa.x = fmaf(ka, cs, sa.x); sa.y = fmaf(ka, sn, sa.y);
    sb.x = fmaf(kb, cs, sb.x); sb.y = fmaf(kb, sn, sb.y);
  }
  tA[(i * HWID + v) * 256 + c] = sa;
  tB[(i * HWID + v) * 256 + c] = sb;
}

// stage 2: DFT over i -> Af[u][v][c] (half-spectrum in v; Hermitian covers rest)
__global__ __launch_bounds__(256) void kfreq2(const float2* __restrict__ tA, const float2* __restrict__ tB,
                                              float2* __restrict__ Af, float2* __restrict__ Bf) {
  int u = blockIdx.x / HWID, v = blockIdx.x % HWID, c = threadIdx.x;
  const float w0 = -6.2831853071795864769f / 128.0f;
  float2 sa = make_float2(0.f, 0.f), sb = make_float2(0.f, 0.f);
#pragma unroll
  for (int i = 0; i < 7; ++i) {
    float ang = w0 * (float)(u * (i - 3));
    float sn, cs;
    sincosf(ang, &sn, &cs);
    float2 a = tA[(i * HWID + v) * 256 + c];
    float2 b = tB[(i * HWID + v) * 256 + c];
    sa.x += a.x * cs - a.y * sn; sa.y += a.x * sn + a.y * cs;
    sb.x += b.x * cs - b.y * sn; sb.y += b.x * sn + b.y * cs;
  }
  Af[(u * HWID + v) * 256 + c] = sa;
  Bf[(u * HWID + v) * 256 + c] = sb;
}

// ---------------- shared 128-pt radix-2 FFT over LDS [128][32] float2 ----------------
// DIF: natural in -> bit-reversed out. CONJ=1 flips twiddle sign (inverse, unscaled).
template <int CONJ>
__device__ __forceinline__ void fft_dif(float2* Xs, const float2* tw, int t) {
  int cc = t & 31, bt = t >> 5;
#pragma unroll
  for (int s = 0; s < 7; ++s) {
    int half = 64 >> s;
#pragma unroll
    for (int r = 0; r < 8; ++r) {
      int bf = bt + (r << 3);
      int q = bf & (half - 1);
      int i0 = ((bf >> (6 - s)) << (7 - s)) + q;
      int i1 = i0 + half;
      float2 a = Xs[i0 * 32 + cc], b = Xs[i1 * 32 + cc];
      Xs[i0 * 32 + cc] = make_float2(a.x + b.x, a.y + b.y);
      float2 d = make_float2(a.x - b.x, a.y - b.y);
      float2 w = tw[q << s];
      if (CONJ) w.y = -w.y;
      Xs[i1 * 32 + cc] = cmulf(d, w);
    }
    __syncthreads();
  }
}

// DIT: bit-reversed in -> natural out, conj twiddles (inverse, unscaled)
__device__ __forceinline__ void ifft_dit(float2* Xs, const float2* tw, int t) {
  int cc = t & 31, bt = t >> 5;
#pragma unroll
  for (int s = 0; s < 7; ++s) {
    int half = 1 << s;
#pragma unroll
    for (int r = 0; r < 8; ++r) {
      int bf = bt + (r << 3);
      int q = bf & (half - 1);
      int i0 = ((bf >> s) << (s + 1)) + q;
      int i1 = i0 + half;
      float2 w = tw[q << (6 - s)];
      w.y = -w.y;
      float2 a = Xs[i0 * 32 + cc];
      float2 bv = cmulf(Xs[i1 * 32 + cc], w);
      Xs[i0 * 32 + cc] = make_float2(a.x + bv.x, a.y + bv.y);
      Xs[i1 * 32 + cc] = make_float2(a.x - bv.x, a.y - bv.y);
    }
    __syncthreads();
  }
}

__device__ __forceinline__ void build_tw(float2* tw, int t) {
  if (t < 64) {
    float sn, cs;
    sincosf(-6.2831853071795864769f * (float)t / 128.0f, &sn, &cs);
    tw[t] = make_float2(cs, sn);
  }
}

// ---------------- pass1: FFT over W (R2C half-spectrum), also emit fp16 x ----------------
__global__ __launch_bounds__(256) void pass1_fftw(const float* __restrict__ x, float2* __restrict__ X1,
                                                  _Float16* __restrict__ xh) {
  __shared__ float2 Xs[128 * 32];
  __shared__ float2 tw[64];
  int t = threadIdx.x, cc = t & 31, pp = t >> 5;
  int c0 = blockIdx.x * 32, h = blockIdx.y, b = blockIdx.z;
  build_tw(tw, t);
  int base = ((b * HGT + h) * WID) * CHN + c0 + cc;
#pragma unroll
  for (int it = 0; it < 16; ++it) {
    int w = pp + it * 8;
    float v = x[base + w * CHN];
    xh[base + w * CHN] = (_Float16)v;
    Xs[w * 32 + cc] = make_float2(v, 0.f);
  }
  __syncthreads();
  fft_dif<0>(Xs, tw, t);
  int obase = ((b * HGT + h) * HWID) * CHN + c0 + cc;
#pragma unroll
  for (int it = 0; it < 16; ++it) {
    int p = pp + it * 8;
    int wt = __brev((unsigned)p) >> 25;
    if (wt < HWID) X1[obase + wt * CHN] = Xs[p * 32 + cc];
  }
}

// ---------------- GEMM (fp16 MFMA) + gate epilogue ----------------
// C-tile 128x128: rows = bhw, cols p = c_local*4 + proj. Epilogue: gates[m][c][4] fp16.
__global__ __launch_bounds__(256) void gemm_gates(const _Float16* __restrict__ xh, const _Float16* __restrict__ Wt,
                                                  const float* __restrict__ bma, const float* __restrict__ bpa,
                                                  const float* __restrict__ bmb, const float* __restrict__ bpb,
                                                  _Float16* __restrict__ gates) {
  __shared__ alignas(16) char smem[33792];  // As 8KB | Bs 8KB; Cs (64x132 f32) overlays
  _Float16* As = (_Float16*)smem;
  _Float16* Bs = (_Float16*)(smem + 8192);
  float* Cs = (float*)smem;

  int t = threadIdx.x;
  int nblk = blockIdx.x, mblk = blockIdx.y;
  int m0 = mblk * 128, p0 = nblk * 128;
  int wv = t >> 6, lane = t & 63;
  int wm = wv >> 1, wn = wv & 1;
  int fr = lane & 15, fk = (lane >> 4) * 8;

  f32x4 acc[4][4] = {};
  const _Float16* Ag = xh + (size_t)m0 * 256;
  const _Float16* Bg = Wt + (size_t)p0 * 256;

  for (int kt = 0; kt < 8; ++kt) {
    int k0 = kt * 32;
#pragma unroll
    for (int iss = 0; iss < 2; ++iss) {
      int i = iss * 256 + t;
      gload_lds16(Ag + (i >> 2) * 256 + k0 + (i & 3) * 8, As + (iss * 256 + wv * 64) * 8);
      gload_lds16(Bg + (i >> 2) * 256 + k0 + (i & 3) * 8, Bs + (iss * 256 + wv * 64) * 8);
    }
    __syncthreads();
    f16x8 af[4], bf[4];
#pragma unroll
    for (int mi = 0; mi < 4; ++mi) af[mi] = *(const f16x8*)&As[(wm * 64 + mi * 16 + fr) * 32 + fk];
#pragma unroll
    for (int ni = 0; ni < 4; ++ni) bf[ni] = *(const f16x8*)&Bs[(wn * 64 + ni * 16 + fr) * 32 + fk];
#pragma unroll
    for (int mi = 0; mi < 4; ++mi)
#pragma unroll
      for (int ni = 0; ni < 4; ++ni)
        acc[mi][ni] = __builtin_amdgcn_mfma_f32_16x16x32_f16(af[mi], bf[ni], acc[mi][ni], 0, 0, 0);
    __syncthreads();
  }

  int cl = t & 31;
  int c = nblk * 32 + cl;
  float vbma = bma[c], vbpa = bpa[c], vbmb = bmb[c], vbpb = bpb[c];

  for (int halfr = 0; halfr < 2; ++halfr) {
    if (wm == halfr) {
#pragma unroll
      for (int mi = 0; mi < 4; ++mi)
#pragma unroll
        for (int ni = 0; ni < 4; ++ni)
#pragma unroll
          for (int r = 0; r < 4; ++r)
            Cs[(mi * 16 + (lane >> 4) * 4 + r) * 132 + wn * 64 + ni * 16 + (lane & 15)] = acc[mi][ni][r];
    }
    __syncthreads();
#pragma unroll
    for (int it = 0; it < 8; ++it) {
      int rl = (t >> 5) + it * 8;
      float4 y = *(const float4*)&Cs[rl * 132 + cl * 4];
      float sa = 1.f / (1.f + __expf(-(y.x + vbma)));
      float sb = 1.f / (1.f + __expf(-(y.z + vbmb)));
      float sna, csa, snb, csb;
      __sincosf(y.y + vbpa, &sna, &csa);
      __sincosf(y.w + vbpb, &snb, &csb);
      int m = m0 + halfr * 64 + rl;
      f16x4 g;
      g[0] = (_Float16)(sa * csa); g[1] = (_Float16)(sa * sna);
      g[2] = (_Float16)(sb * csb); g[3] = (_Float16)(sb * snb);
      *(f16x4*)&gates[(size_t)m * 1024 + c * 4] = g;
    }
    __syncthreads();
  }
}

// ---------------- pass2: per column w<=64: FFT_H, pointwise G_herm*x_f, IFFT_H (in place) --------
__global__ __launch_bounds__(256) void pass2_col(float2* __restrict__ X1, const _Float16* __restrict__ gates,
                                                 const float2* __restrict__ Af, const float2* __restrict__ Bf) {
  __shared__ float2 Xs[128 * 32];
  __shared__ float2 tw[64];
  int t = threadIdx.x, cc = t & 31, pp = t >> 5;
  int c0 = blockIdx.x * 32, w = blockIdx.y, b = blockIdx.z;
  build_tw(tw, t);
  int colbase = ((b * HGT) * HWID + w) * CHN + c0 + cc;  // + h*HWID*CHN
#pragma unroll
  for (int it = 0; it < 16; ++it) {
    int h = pp + it * 8;
    Xs[h * 32 + cc] = X1[colbase + h * HWID * CHN];
  }
  __syncthreads();
  fft_dif<0>(Xs, tw, t);  // position p holds x_f[u=rev(p)][w]

  int wp = (128 - w) & 127;
  const float sc = 3.0517578125e-05f;  // 0.5 / 16384  (Hermitian half + ifft2 norm)
#pragma unroll 1
  for (int it = 0; it < 16; ++it) {
    int p = pp + it * 8;
    int u = __brev((unsigned)p) >> 25;
    int up = (128 - u) & 127;
    int gidx1 = (((b * HGT + u) * WID + w) * CHN + c0 + cc) * 4;
    int gidx2 = (((b * HGT + up) * WID + wp) * CHN + c0 + cc) * 4;
    f16x4 g1 = *(const f16x4*)&gates[gidx1];
    f16x4 g2 = *(const f16x4*)&gates[gidx2];
    int aidx = (u * HWID + w) * CHN + c0 + cc;
    float2 A1 = Af[aidx];
    float2 B1 = Bf[aidx];
    // bin (u,w)
    float2 a1 = cmulf(make_float2((float)g1[0], (float)g1[1]), A1);
    float2 S1 = make_float2(a1.x + 1.f, a1.y);
#pragma unroll
    for (int q = 0; q < 6; ++q) { S1 = cmulf(a1, S1); S1.x += 1.f; }
    float2 G1 = cmulf(cmulf(make_float2((float)g1[2], (float)g1[3]), B1), S1);
    // partner bin (-u,-w): Af/Bf are conj (real kernels)
    float2 A2 = make_float2(A1.x, -A1.y), B2 = make_float2(B1.x, -B1.y);
    float2 a2 = cmulf(make_float2((float)g2[0], (float)g2[1]), A2);
    float2 S2 = make_float2(a2.x + 1.f, a2.y);
#pragma unroll
    for (int q = 0; q < 6; ++q) { S2 = cmulf(a2, S2); S2.x += 1.f; }
    float2 G2 = cmulf(cmulf(make_float2((float)g2[2], (float)g2[3]), B2), S2);
    float2 Gh = make_float2((G1.x + G2.x) * sc, (G1.y - G2.y) * sc);
    Xs[p * 32 + cc] = cmulf(Xs[p * 32 + cc], Gh);
  }
  __syncthreads();
  ifft_dit(Xs, tw, t);  // natural h order
#pragma unroll
  for (int it = 0; it < 16; ++it) {
    int h = pp + it * 8;
    X1[colbase + h * HWID * CHN] = Xs[h * 32 + cc];
  }
}

// ---------------- pass3: Hermitian-complete + inverse FFT over W, write real ----------------
__global__ __launch_bounds__(256) void pass3_ifftw(const float2* __restrict__ X1, float* __restrict__ out) {
  __shared__ float2 Xs[128 * 32];
  __shared__ float2 tw[64];
  int t = threadIdx.x, cc = t & 31, pp = t >> 5;
  int c0 = blockIdx.x * 32, h = blockIdx.y, b = blockIdx.z;
  build_tw(tw, t);
  int rowbase = ((b * HGT + h) * HWID) * CHN + c0 + cc;
#pragma unroll
  for (int it = 0; it < 9; ++it) {
    int w = pp + it * 8;
    if (w < HWID) Xs[w * 32 + cc] = X1[rowbase + w * CHN];
  }
  __syncthreads();
#pragma unroll
  for (int it = 0; it < 16; ++it) {
    int w = pp + it * 8;
    if (w > 64) {
      float2 v = Xs[(128 - w) * 32 + cc];
      Xs[w * 32 + cc] = make_float2(v.x, -v.y);
    }
  }
  __syncthreads();
  fft_dif<1>(Xs, tw, t);  // inverse (unscaled; scaling folded in pass2), bitrev out
  int obase = ((b * HGT + h) * WID) * CHN + c0 + cc;
#pragma unroll
  for (int it = 0; it < 16; ++it) {
    int p = pp + it * 8;
    int wt = __brev((unsigned)p) >> 25;
    out[obase + wt * CHN] = Xs[p * 32 + cc].x;
  }
}

extern "C" void kernel_launch(void* const* d_in, const int* in_sizes, int n_in,
                              void* d_out, int out_size, void* d_ws, size_t ws_size,
                              hipStream_t stream) {
  (void)in_sizes; (void)n_in; (void)out_size;
  const float* x   = (const float*)d_in[0];
  const float* KA  = (const float*)d_in[1];
  const float* KB  = (const float*)d_in[2];
  const float* Wma = (const float*)d_in[3];
  const float* bma = (const float*)d_in[4];
  const float* Wpa = (const float*)d_in[5];
  const float* bpa = (const float*)d_in[6];
  const float* Wmb = (const float*)d_in[7];
  const float* bmb = (const float*)d_in[8];
  const float* Wpb = (const float*)d_in[9];
  const float* bpb = (const float*)d_in[10];
  float* out = (float*)d_out;

  char* ws = (char*)d_ws;
  size_t off = 0;
  auto alloc = [&](size_t bytes) -> char* {
    char* p = ws + off;
    off += (bytes + 255) & ~(size_t)255;
    return p;
  };
  const size_t M = (size_t)BATCH * HGT * WID;              // 131072 rows
  _Float16* Wt    = (_Float16*)alloc(1024 * 256 * 2);
  _Float16* xh    = (_Float16*)alloc(M * CHN * 2);
  _Float16* gates = (_Float16*)alloc(M * CHN * 4 * 2);
  float2*   X1    = (float2*)alloc((size_t)BATCH * HGT * HWID * CHN * 8);
  float2*   Af    = (float2*)alloc((size_t)HGT * HWID * CHN * 8);
  float2*   Bf    = (float2*)alloc((size_t)HGT * HWID * CHN * 8);
  float2*   tA    = (float2*)alloc((size_t)7 * HWID * CHN * 8);
  float2*   tB    = (float2*)alloc((size_t)7 * HWID * CHN * 8);
  if (off > ws_size) return;  // workspace too small: leaves output zero (diagnostic)

  prep_w<<<dim3(256), dim3(256), 0, stream>>>(Wma, Wpa, Wmb, Wpb, Wt);
  kfreq1<<<dim3(7 * HWID), dim3(256), 0, stream>>>(KA, KB, tA, tB);
  kfreq2<<<dim3(128 * HWID), dim3(256), 0, stream>>>(tA, tB, Af, Bf);
  pass1_fftw<<<dim3(CHN / 32, HGT, BATCH), dim3(256), 0, stream>>>(x, X1, xh);
  gemm_gates<<<dim3(8, 1024), dim3(256), 0, stream>>>(xh, Wt, bma, bpa, bmb, bpb, gates);
  pass2_col<<<dim3(CHN / 32, HWID, BATCH), dim3(256), 0, stream>>>(X1, gates, Af, Bf);
  pass3_ifftw<<<dim3(CHN / 32, HGT, BATCH), dim3(256), 0, stream>>>(X1, out);
}